// Round 6
// baseline (136.501 us; speedup 1.0000x reference)
//
#include <hip/hip_runtime.h>
#include <math.h>

#define NTHR 256
#define WAVES_PER_BLOCK 4
// 62500 tiles / (3125 blk x 4 waves) = exactly 5 tiles per wave: zero tail
// imbalance (vs 95.4% makespan utilization at 4096 blk) and 5-tile
// amortization of the ~90-load weight preamble.
#define NBLK 3125

typedef __attribute__((ext_vector_type(8))) _Float16 f16x8;   // MFMA A/B frag (4 VGPRs)
typedef __attribute__((ext_vector_type(2))) _Float16 half2v;
typedef __attribute__((ext_vector_type(4))) float f32x4;      // MFMA C/D frag + packed math
typedef __attribute__((ext_vector_type(4))) unsigned uint4v;

#define CEXP 28.85390082f     // 20 * log2(e)
#define KLOG 0.03465735903f   // ln(2) / 20

// raw gfx950 transcendentals: v_exp_f32 is 2^x, v_log_f32 is log2(x)
#define EXP2F(v) __builtin_amdgcn_exp2f(v)
#define LOG2F(v) __builtin_amdgcn_logf(v)

static __device__ __forceinline__ f32x4 splat4(float v) { return (f32x4){v, v, v, v}; }

// Vectorized softplus(beta=20) + derivative (proven fastest variant, R0).
// h = max(z,0) + KLOG*l, l = log2(1+2^(-|CEXP z|)); s = 1 - 2^(-CEXP*max(z,0) - l)
static __device__ __forceinline__ void act_hs4(f32x4 z, f32x4& h, f32x4& s) {
    f32x4 az = __builtin_elementwise_abs(splat4(CEXP) * z);
    f32x4 e;
    #pragma unroll
    for (int i = 0; i < 4; ++i) e[i] = EXP2F(-az[i]);
    f32x4 p = splat4(1.0f) + e;
    f32x4 l;
    #pragma unroll
    for (int i = 0; i < 4; ++i) l[i] = LOG2F(p[i]);
    f32x4 zp = __builtin_elementwise_max(z, splat4(0.0f));
    f32x4 q  = __builtin_elementwise_fma(splat4(-CEXP), zp, -l);
    f32x4 t;
    #pragma unroll
    for (int i = 0; i < 4; ++i) t[i] = EXP2F(q[i]);
    s = splat4(1.0f) - t;
    h = __builtin_elementwise_fma(splat4(KLOG), l, zp);
}

// sigmoid(20z) vectorized; select-free (exp2 overflow->inf, rcp(inf)->0)
static __device__ __forceinline__ f32x4 sigmoid4(f32x4 z) {
    f32x4 cz = splat4(-CEXP) * z;
    f32x4 e;
    #pragma unroll
    for (int i = 0; i < 4; ++i) e[i] = EXP2F(cz[i]);
    f32x4 p = splat4(1.0f) + e;
    f32x4 r;
    #pragma unroll
    for (int i = 0; i < 4; ++i) r[i] = __builtin_amdgcn_rcpf(p[i]);
    return r;
}

// pack 2 floats -> 2 f16 in one v_cvt_pkrtz_f16_f32
static __device__ __forceinline__ unsigned pk(float a, float b) {
    return __builtin_bit_cast(unsigned, __builtin_amdgcn_cvt_pkrtz(a, b));
}

// two f32x4 chunks -> single-f16 B operand (tangent streams)
static __device__ __forceinline__ f16x8 pack8v(const f32x4& a, const f32x4& b) {
    uint4v u = {pk(a[0], a[1]), pk(a[2], a[3]), pk(b[0], b[1]), pk(b[2], b[3])};
    return __builtin_bit_cast(f16x8, u);
}
// two f32x4 chunks -> f16 hi/lo split B operand (forward stream, residual ~2^-22)
static __device__ __forceinline__ void fsplit8v(const f32x4& a, const f32x4& b,
                                                f16x8& hi, f16x8& lo) {
    unsigned h[4], l[4];
    #pragma unroll
    for (int p2 = 0; p2 < 2; ++p2) {
        float u0 = a[2 * p2], u1 = a[2 * p2 + 1];
        unsigned hp = pk(u0, u1);
        half2v hh = __builtin_bit_cast(half2v, hp);
        h[p2] = hp;
        l[p2] = pk(u0 - (float)hh[0], u1 - (float)hh[1]);
        float w0 = b[2 * p2], w1 = b[2 * p2 + 1];
        unsigned hq = pk(w0, w1);
        half2v hh2 = __builtin_bit_cast(half2v, hq);
        h[2 + p2] = hq;
        l[2 + p2] = pk(w0 - (float)hh2[0], w1 - (float)hh2[1]);
    }
    hi = __builtin_bit_cast(f16x8, (uint4v){h[0], h[1], h[2], h[3]});
    lo = __builtin_bit_cast(f16x8, (uint4v){l[0], l[1], l[2], l[3]});
}

// forward, single-f16 weight: D += W*Bh + W*Bl
static __device__ __forceinline__ f32x4 mfma2f(f16x8 w, f16x8 bh, f16x8 bl, f32x4 c) {
    c = __builtin_amdgcn_mfma_f32_16x16x32_f16(w, bh, c, 0, 0, 0);
    c = __builtin_amdgcn_mfma_f32_16x16x32_f16(w, bl, c, 0, 0, 0);
    return c;
}
// tangent, single-f16 both sides: one MFMA
static __device__ __forceinline__ f32x4 mfma1t(f16x8 w, f16x8 b, f32x4 c) {
    return __builtin_amdgcn_mfma_f32_16x16x32_f16(w, b, c, 0, 0, 0);
}

// __launch_bounds__(256, 3): ~170-reg budget. R5's min=4 (128 regs) produced
// ~13 MB/dispatch of scratch spills (FETCH+WRITE signature) for only +2%;
// the stream-serial body's natural pressure (~150 unified regs) fits in 170
// with no spills while keeping ~3 waves/SIMD.
__global__ void __launch_bounds__(NTHR, 3)
presdiv_kernel(const float* __restrict__ x,
               const float* __restrict__ W1, const float* __restrict__ b1,
               const float* __restrict__ W2, const float* __restrict__ b2,
               const float* __restrict__ W3, const float* __restrict__ b3,
               const float* __restrict__ W4,
               float* __restrict__ out, int N)
{
    const int lane = threadIdx.x & 63;
    const int wid  = threadIdx.x >> 6;
    const int n16  = lane & 15;        // sample-within-tile / MFMA col
    const int g    = lane >> 4;        // quad

    // ---- persistent weights (per lane), single f16 (RTN) ----
    f16x8 w2[2], w3[2];
    #pragma unroll
    for (int h = 0; h < 2; ++h) {
        #pragma unroll
        for (int j = 0; j < 8; ++j) {
            const int k2 = g * 8 + j;
            w2[h][j] = (_Float16)W2[k2 * 32 + 16 * h + n16];
            const int k3 = (j < 4) ? (4 * g + j) : (16 + 4 * g + (j - 4));
            w3[h][j] = (_Float16)W3[k3 * 32 + 16 * h + n16];
        }
    }
    // layer-1 rows + bias, vectorized in 2 chunks of 4 features
    f32x4 w1v[3][2], bb1v[2];
    #pragma unroll
    for (int c = 0; c < 2; ++c)
        #pragma unroll
        for (int i = 0; i < 4; ++i) {
            const int j = 4 * c + i;
            bb1v[c][i] = b1[g * 8 + j];
            #pragma unroll
            for (int d = 0; d < 3; ++d) w1v[d][c][i] = W1[d * 32 + g * 8 + j];
        }
    // C-layout biases + W4 column-vectors (k fixed, 4 rows per vector)
    f32x4 bb2v[2], bb3v[2], w4c[2][3];
    #pragma unroll
    for (int h = 0; h < 2; ++h)
        #pragma unroll
        for (int r = 0; r < 4; ++r) {
            const int row = 16 * h + 4 * g + r;
            bb2v[h][r] = b2[row];
            bb3v[h][r] = b3[row];
            #pragma unroll
            for (int k = 0; k < 3; ++k) w4c[h][k][r] = W4[row * 3 + k];
        }

    const int ntiles = (N + 15) >> 4;
    const int nwaves = gridDim.x * WAVES_PER_BLOCK;
    const f32x4 vzero = {0.f, 0.f, 0.f, 0.f};

    for (int tile = blockIdx.x * WAVES_PER_BLOCK + wid; tile < ntiles; tile += nwaves) {
        int s = tile * 16 + n16;
        if (s >= N) s = N - 1;
        const f32x4 X0 = splat4(x[3 * s + 0]);
        const f32x4 X1 = splat4(x[3 * s + 1]);
        const f32x4 X2 = splat4(x[3 * s + 2]);

        // ---- layer 1 (exact fp32, packed), directly in B-layout ----
        f32x4 vFv[2], t0v[2], t1v[2], t2v[2];
        #pragma unroll
        for (int c = 0; c < 2; ++c) {
            f32x4 z = __builtin_elementwise_fma(X0, w1v[0][c], bb1v[c]);
            z = __builtin_elementwise_fma(X1, w1v[1][c], z);
            z = __builtin_elementwise_fma(X2, w1v[2][c], z);
            f32x4 hv, sv;
            act_hs4(z, hv, sv);
            vFv[c] = hv;
            t0v[c] = sv * w1v[0][c];
            t1v[c] = sv * w1v[1][c];
            t2v[c] = sv * w1v[2][c];
        }
        // pack tangent B-operands immediately: 3 x f16x8 (12 regs) replaces
        // 6 x f32x4 (24 regs) of live state for the rest of the tile.
        const f16x8 tb0 = pack8v(t0v[0], t0v[1]);
        const f16x8 tb1 = pack8v(t1v[0], t1v[1]);
        const f16x8 tb2 = pack8v(t2v[0], t2v[1]);

        // ---- forward path to completion: aF -> act -> zF -> S ----
        f16x8 bh, bl;
        fsplit8v(vFv[0], vFv[1], bh, bl);
        f32x4 aF0 = mfma2f(w2[0], bh, bl, bb2v[0]);
        f32x4 aF1 = mfma2f(w2[1], bh, bl, bb2v[1]);

        f32x4 hF0, hF1, sv0, sv1;
        act_hs4(aF0, hF0, sv0);
        act_hs4(aF1, hF1, sv1);

        fsplit8v(hF0, hF1, bh, bl);
        const f32x4 zF0 = mfma2f(w3[0], bh, bl, bb3v[0]);
        const f32x4 zF1 = mfma2f(w3[1], bh, bl, bb3v[1]);
        const f32x4 S0 = sigmoid4(zF0);
        const f32x4 S1 = sigmoid4(zF1);

        // ---- tangent streams, one at a time (minimal live state) ----
        // combine: O0 =  T1*W4[:,0] + T2*W4[:,1]
        //          O1 = -T0*W4[:,0] + T2*W4[:,2]
        //          O2 = -T0*W4[:,1] - T1*W4[:,2]
        f32x4 O0 = vzero, O1 = vzero, O2 = vzero;

        {   // d = 0 -> T0
            f32x4 a0 = mfma1t(w2[0], tb0, vzero) * sv0;
            f32x4 a1 = mfma1t(w2[1], tb0, vzero) * sv1;
            const f16x8 tp = pack8v(a0, a1);
            const f32x4 Ta = S0 * mfma1t(w3[0], tp, vzero);
            const f32x4 Tb = S1 * mfma1t(w3[1], tp, vzero);
            O1 = __builtin_elementwise_fma(-Ta, w4c[0][0],
                 __builtin_elementwise_fma(-Tb, w4c[1][0], O1));
            O2 = __builtin_elementwise_fma(-Ta, w4c[0][1],
                 __builtin_elementwise_fma(-Tb, w4c[1][1], O2));
        }
        {   // d = 1 -> T1
            f32x4 a0 = mfma1t(w2[0], tb1, vzero) * sv0;
            f32x4 a1 = mfma1t(w2[1], tb1, vzero) * sv1;
            const f16x8 tp = pack8v(a0, a1);
            const f32x4 Ta = S0 * mfma1t(w3[0], tp, vzero);
            const f32x4 Tb = S1 * mfma1t(w3[1], tp, vzero);
            O0 = __builtin_elementwise_fma(Ta, w4c[0][0],
                 __builtin_elementwise_fma(Tb, w4c[1][0], O0));
            O2 = __builtin_elementwise_fma(-Ta, w4c[0][2],
                 __builtin_elementwise_fma(-Tb, w4c[1][2], O2));
        }
        {   // d = 2 -> T2
            f32x4 a0 = mfma1t(w2[0], tb2, vzero) * sv0;
            f32x4 a1 = mfma1t(w2[1], tb2, vzero) * sv1;
            const f16x8 tp = pack8v(a0, a1);
            const f32x4 Ta = S0 * mfma1t(w3[0], tp, vzero);
            const f32x4 Tb = S1 * mfma1t(w3[1], tp, vzero);
            O0 = __builtin_elementwise_fma(Ta, w4c[0][1],
                 __builtin_elementwise_fma(Tb, w4c[1][1], O0));
            O1 = __builtin_elementwise_fma(Ta, w4c[0][2],
                 __builtin_elementwise_fma(Tb, w4c[1][2], O1));
        }

        float o0 = (O0[0] + O0[1]) + (O0[2] + O0[3]);
        float o1 = (O1[0] + O1[1]) + (O1[2] + O1[3]);
        float o2 = (O2[0] + O2[1]) + (O2[2] + O2[3]);

        o0 += __shfl_xor(o0, 16); o0 += __shfl_xor(o0, 32);
        o1 += __shfl_xor(o1, 16); o1 += __shfl_xor(o1, 32);
        o2 += __shfl_xor(o2, 16); o2 += __shfl_xor(o2, 32);

        if (g == 0) {
            out[3 * s + 0] = o0;
            out[3 * s + 1] = o1;
            out[3 * s + 2] = o2;
        }
    }
}

extern "C" void kernel_launch(void* const* d_in, const int* in_sizes, int n_in,
                              void* d_out, int out_size, void* d_ws, size_t ws_size,
                              hipStream_t stream)
{
    const float* x  = (const float*)d_in[0];
    const float* W1 = (const float*)d_in[1];
    const float* b1 = (const float*)d_in[2];
    const float* W2 = (const float*)d_in[3];
    const float* b2 = (const float*)d_in[4];
    const float* W3 = (const float*)d_in[5];
    const float* b3 = (const float*)d_in[6];
    const float* W4 = (const float*)d_in[7];
    // d_in[8] = b4 unused: constant offset cancels in the Jacobian.
    float* out = (float*)d_out;

    const int N = in_sizes[0] / 3;
    presdiv_kernel<<<NBLK, NTHR, 0, stream>>>(x, W1, b1, W2, b2, W3, b3, W4, out, N);
}